// Round 1
// baseline (33206.900 us; speedup 1.0000x reference)
//
#include <hip/hip_runtime.h>
#include <hip/hip_bf16.h>
#include <math.h>

#define B_   8
#define S_   512
#define H_   768
#define L_   12
#define NHD_ 12
#define DH_  64
#define DFF_ 3072
#define NL_  19

__device__ __forceinline__ float gelu_f(float x) {
    const float c = 0.7978845608028654f; // sqrt(2/pi)
    float x3 = x * x * x;
    return 0.5f * x * (1.0f + tanhf(c * (x + 0.044715f * x3)));
}

// ---------------------------------------------------------------------------
// GEMM: C[M,N] = epi(A[M,K] @ W[K,N] + bias[N] [+ R]) ; EPI: 0 none, 1 gelu, 2 residual
// 64x64 tile, 256 threads, 4x4 microtile, K-step 16. M %64==0, K %16==0 assumed.
// ---------------------------------------------------------------------------
template <int EPI>
__global__ __launch_bounds__(256) void gemm_kernel(
    const float* __restrict__ A, const float* __restrict__ W,
    const float* __restrict__ bias, const float* __restrict__ R,
    float* __restrict__ C, int M, int N, int K)
{
    __shared__ float As[16][65];   // [k][m], padded
    __shared__ float Ws[16][64];   // [k][n]
    const int tid = threadIdx.x;
    const int tx = tid & 15;   // -> n
    const int ty = tid >> 4;   // -> m
    const int mbase = blockIdx.y * 64;
    const int nbase = blockIdx.x * 64;

    float acc[4][4] = {};

    for (int kk = 0; kk < K; kk += 16) {
        #pragma unroll
        for (int r = 0; r < 4; ++r) {
            int idx = r * 256 + tid;
            int m  = idx >> 4;
            int k4 = idx & 15;
            As[k4][m] = A[(size_t)(mbase + m) * K + kk + k4];
        }
        #pragma unroll
        for (int r = 0; r < 4; ++r) {
            int idx = r * 256 + tid;
            int n  = idx & 63;
            int k4 = idx >> 6;
            int gn = nbase + n;
            Ws[k4][n] = (gn < N) ? W[(size_t)(kk + k4) * N + gn] : 0.0f;
        }
        __syncthreads();
        #pragma unroll
        for (int k = 0; k < 16; ++k) {
            float a[4], w[4];
            #pragma unroll
            for (int i = 0; i < 4; ++i) a[i] = As[k][ty * 4 + i];
            #pragma unroll
            for (int j = 0; j < 4; ++j) w[j] = Ws[k][tx * 4 + j];
            #pragma unroll
            for (int i = 0; i < 4; ++i)
                #pragma unroll
                for (int j = 0; j < 4; ++j)
                    acc[i][j] = fmaf(a[i], w[j], acc[i][j]);
        }
        __syncthreads();
    }

    #pragma unroll
    for (int i = 0; i < 4; ++i) {
        int gm = mbase + ty * 4 + i;
        #pragma unroll
        for (int j = 0; j < 4; ++j) {
            int gn = nbase + tx * 4 + j;
            if (gn < N) {
                float v = acc[i][j] + bias[gn];
                if (EPI == 1) v = gelu_f(v);
                if (EPI == 2) v += R[(size_t)gm * N + gn];
                C[(size_t)gm * N + gn] = v;
            }
        }
    }
}

// ---------------------------------------------------------------------------
// Row LayerNorm: out[row,:] = (x-mean)*rsqrt(var+eps)*s + b, H_=768, 256 thr
// ---------------------------------------------------------------------------
__global__ __launch_bounds__(256) void ln_kernel(
    const float* __restrict__ in, const float* __restrict__ sc,
    const float* __restrict__ bi, float* __restrict__ out)
{
    const int row = blockIdx.x;
    const int tid = threadIdx.x;
    const float* x = in + (size_t)row * H_;
    float v[3], s0 = 0.f, s1 = 0.f;
    #pragma unroll
    for (int r = 0; r < 3; ++r) {
        v[r] = x[tid + r * 256];
        s0 += v[r]; s1 += v[r] * v[r];
    }
    __shared__ float red[8];
    __shared__ float stat[2];
    #pragma unroll
    for (int o = 32; o > 0; o >>= 1) { s0 += __shfl_down(s0, o); s1 += __shfl_down(s1, o); }
    if ((tid & 63) == 0) { red[tid >> 6] = s0; red[4 + (tid >> 6)] = s1; }
    __syncthreads();
    if (tid == 0) {
        float t0 = red[0] + red[1] + red[2] + red[3];
        float t1 = red[4] + red[5] + red[6] + red[7];
        float mean = t0 / H_;
        float var  = t1 / H_ - mean * mean;
        stat[0] = mean;
        stat[1] = rsqrtf(var + 1e-12f);
    }
    __syncthreads();
    float mean = stat[0], rstd = stat[1];
    float* o = out + (size_t)row * H_;
    #pragma unroll
    for (int r = 0; r < 3; ++r) {
        int i = tid + r * 256;
        o[i] = (v[r] - mean) * rstd * sc[i] + bi[i];
    }
}

// ---------------------------------------------------------------------------
// Embedding gather + LN
// ---------------------------------------------------------------------------
__global__ __launch_bounds__(256) void embed_ln_kernel(
    const int* __restrict__ ids, const float* __restrict__ tok,
    const float* __restrict__ pos, const float* __restrict__ sc,
    const float* __restrict__ bi, float* __restrict__ out)
{
    const int row = blockIdx.x;          // b*S + s
    const int spos = row & (S_ - 1);
    const int tid = threadIdx.x;
    const int id = ids[row];
    const float* t = tok + (size_t)id * H_;
    const float* p = pos + (size_t)spos * H_;
    float v[3], s0 = 0.f, s1 = 0.f;
    #pragma unroll
    for (int r = 0; r < 3; ++r) {
        int i = tid + r * 256;
        v[r] = t[i] + p[i];
        s0 += v[r]; s1 += v[r] * v[r];
    }
    __shared__ float red[8];
    __shared__ float stat[2];
    #pragma unroll
    for (int o = 32; o > 0; o >>= 1) { s0 += __shfl_down(s0, o); s1 += __shfl_down(s1, o); }
    if ((tid & 63) == 0) { red[tid >> 6] = s0; red[4 + (tid >> 6)] = s1; }
    __syncthreads();
    if (tid == 0) {
        float t0 = red[0] + red[1] + red[2] + red[3];
        float t1 = red[4] + red[5] + red[6] + red[7];
        float mean = t0 / H_;
        float var  = t1 / H_ - mean * mean;
        stat[0] = mean;
        stat[1] = rsqrtf(var + 1e-12f);
    }
    __syncthreads();
    float mean = stat[0], rstd = stat[1];
    float* o = out + (size_t)row * H_;
    #pragma unroll
    for (int r = 0; r < 3; ++r) {
        int i = tid + r * 256;
        o[i] = (v[r] - mean) * rstd * sc[i] + bi[i];
    }
}

// ---------------------------------------------------------------------------
// Fused attention: one block per (q-row, head, batch). scores in LDS.
// ---------------------------------------------------------------------------
__global__ __launch_bounds__(256) void attn_kernel(
    const float* __restrict__ q, const float* __restrict__ k,
    const float* __restrict__ v, const int* __restrict__ mask,
    float* __restrict__ ctx)
{
    const int sq = blockIdx.x, hh = blockIdx.y, b = blockIdx.z;
    const int tid = threadIdx.x;
    __shared__ float qv[64];
    __shared__ float sc[S_];
    __shared__ float part[256];
    __shared__ float red[4];
    __shared__ float stat[2];

    const size_t rowq = ((size_t)b * S_ + sq) * H_ + hh * DH_;
    if (tid < 64) qv[tid] = q[rowq + tid];
    __syncthreads();

    for (int kk = tid; kk < S_; kk += 256) {
        const float* kp = k + ((size_t)b * S_ + kk) * H_ + hh * DH_;
        float dot = 0.f;
        #pragma unroll
        for (int d = 0; d < DH_; d += 4)
            dot += qv[d] * kp[d] + qv[d+1] * kp[d+1] + qv[d+2] * kp[d+2] + qv[d+3] * kp[d+3];
        float mf = (float)mask[b * S_ + kk];
        sc[kk] = dot * 0.125f + (1.0f - mf) * -1e9f;
    }
    __syncthreads();

    float lm = -3.4e38f;
    for (int kk = tid; kk < S_; kk += 256) lm = fmaxf(lm, sc[kk]);
    #pragma unroll
    for (int o = 32; o > 0; o >>= 1) lm = fmaxf(lm, __shfl_down(lm, o));
    if ((tid & 63) == 0) red[tid >> 6] = lm;
    __syncthreads();
    if (tid == 0) stat[0] = fmaxf(fmaxf(red[0], red[1]), fmaxf(red[2], red[3]));
    __syncthreads();
    float smax = stat[0];

    float ls = 0.f;
    for (int kk = tid; kk < S_; kk += 256) {
        float e = __expf(sc[kk] - smax);
        sc[kk] = e;
        ls += e;
    }
    #pragma unroll
    for (int o = 32; o > 0; o >>= 1) ls += __shfl_down(ls, o);
    if ((tid & 63) == 0) red[tid >> 6] = ls;
    __syncthreads();
    if (tid == 0) stat[1] = 1.0f / (red[0] + red[1] + red[2] + red[3]);
    __syncthreads();
    float inv = stat[1];

    const int d = tid & 63;
    const int chunk = tid >> 6;
    float acc = 0.f;
    const size_t vbase = (size_t)b * S_ * H_ + hh * DH_ + d;
    for (int kk = chunk * 128; kk < chunk * 128 + 128; ++kk)
        acc += sc[kk] * v[vbase + (size_t)kk * H_];
    part[tid] = acc;
    __syncthreads();
    if (tid < 64)
        ctx[rowq + tid] = (part[tid] + part[tid + 64] + part[tid + 128] + part[tid + 192]) * inv;
}

// ---------------------------------------------------------------------------
// CRF numerator per batch
// ---------------------------------------------------------------------------
__global__ __launch_bounds__(256) void crf_num_kernel(
    const float* __restrict__ logits, const int* __restrict__ labels,
    const int* __restrict__ mask, const float* __restrict__ start_trans,
    const float* __restrict__ end_trans, const float* __restrict__ trans,
    float* __restrict__ numb)
{
    const int b = blockIdx.x;
    const int tid = threadIdx.x;
    float lsum = 0.f, lmask = 0.f;
    for (int t = tid; t < S_; t += 256) {
        float mf = (float)mask[b * S_ + t];
        lmask += mf;
        if (t >= 1) {
            int lp = labels[b * S_ + t - 1];
            int lc = labels[b * S_ + t];
            float em = logits[((size_t)b * S_ + t) * NL_ + lc];
            lsum += (trans[lp * NL_ + lc] + em) * mf;
        }
    }
    __shared__ float red[8];
    #pragma unroll
    for (int o = 32; o > 0; o >>= 1) { lsum += __shfl_down(lsum, o); lmask += __shfl_down(lmask, o); }
    if ((tid & 63) == 0) { red[tid >> 6] = lsum; red[4 + (tid >> 6)] = lmask; }
    __syncthreads();
    if (tid == 0) {
        float ts = red[0] + red[1] + red[2] + red[3];
        float tm = red[4] + red[5] + red[6] + red[7];
        int l0 = labels[b * S_];
        float nm = start_trans[l0] + logits[(size_t)b * S_ * NL_ + l0] + ts;
        int last = (int)tm - 1;
        int lt = labels[b * S_ + last];
        nm += end_trans[lt];
        numb[b] = nm;
    }
}

// ---------------------------------------------------------------------------
// CRF forward recursion (denominator) per batch; 64 threads, lanes j<19 live
// ---------------------------------------------------------------------------
__global__ __launch_bounds__(64) void crf_fwd_kernel(
    const float* __restrict__ logits, const int* __restrict__ mask,
    const float* __restrict__ start_trans, const float* __restrict__ end_trans,
    const float* __restrict__ trans, float* __restrict__ denb)
{
    const int b = blockIdx.x;
    const int tid = threadIdx.x;
    __shared__ float alpha[NL_];
    __shared__ float tr[NL_ * NL_];
    for (int i = tid; i < NL_ * NL_; i += 64) tr[i] = trans[i];
    if (tid < NL_) alpha[tid] = start_trans[tid] + logits[(size_t)b * S_ * NL_ + tid];
    __syncthreads();
    for (int t = 1; t < S_; ++t) {
        float nxt = 0.f;
        if (tid < NL_) {
            float m = -3.4e38f;
            #pragma unroll
            for (int i = 0; i < NL_; ++i) m = fmaxf(m, alpha[i] + tr[i * NL_ + tid]);
            float s = 0.f;
            #pragma unroll
            for (int i = 0; i < NL_; ++i) s += expf(alpha[i] + tr[i * NL_ + tid] - m);
            nxt = logits[((size_t)b * S_ + t) * NL_ + tid] + m + logf(s);
        }
        __syncthreads();
        if (tid < NL_ && mask[b * S_ + t] > 0) alpha[tid] = nxt;
        __syncthreads();
    }
    if (tid == 0) {
        float m = -3.4e38f;
        for (int i = 0; i < NL_; ++i) m = fmaxf(m, alpha[i] + end_trans[i]);
        float s = 0.f;
        for (int i = 0; i < NL_; ++i) s += expf(alpha[i] + end_trans[i] - m);
        denb[b] = m + logf(s);
    }
}

__global__ void finalize_kernel(const float* __restrict__ numb,
                                const float* __restrict__ denb,
                                float* __restrict__ out)
{
    if (threadIdx.x == 0 && blockIdx.x == 0) {
        float s = 0.f;
        for (int b = 0; b < B_; ++b) s += denb[b] - numb[b];
        out[0] = s;
    }
}

// ---------------------------------------------------------------------------
extern "C" void kernel_launch(void* const* d_in, const int* in_sizes, int n_in,
                              void* d_out, int out_size, void* d_ws, size_t ws_size,
                              hipStream_t stream)
{
    const int*   input_ids = (const int*)d_in[0];
    const int*   attn_mask = (const int*)d_in[1];
    const int*   labels    = (const int*)d_in[2];
    const float* token_emb = (const float*)d_in[3];
    const float* pos_emb   = (const float*)d_in[4];
    const float* ln_emb_s  = (const float*)d_in[5];
    const float* ln_emb_b  = (const float*)d_in[6];
    const float* Wq  = (const float*)d_in[7];
    const float* bq  = (const float*)d_in[8];
    const float* Wk  = (const float*)d_in[9];
    const float* bk  = (const float*)d_in[10];
    const float* Wv  = (const float*)d_in[11];
    const float* bv  = (const float*)d_in[12];
    const float* Wo  = (const float*)d_in[13];
    const float* bo  = (const float*)d_in[14];
    const float* ln1s = (const float*)d_in[15];
    const float* ln1b = (const float*)d_in[16];
    const float* W1  = (const float*)d_in[17];
    const float* b1  = (const float*)d_in[18];
    const float* W2  = (const float*)d_in[19];
    const float* b2  = (const float*)d_in[20];
    const float* ln2s = (const float*)d_in[21];
    const float* ln2b = (const float*)d_in[22];
    const float* cls_W = (const float*)d_in[23];
    const float* cls_b = (const float*)d_in[24];
    const float* start_trans = (const float*)d_in[25];
    const float* end_trans   = (const float*)d_in[26];
    const float* trans       = (const float*)d_in[27];

    float* ws = (float*)d_ws;
    const size_t NX = (size_t)B_ * S_ * H_;          // 3,145,728
    float* x    = ws;
    float* y    = x + NX;
    float* qb   = y + NX;
    float* kb   = qb + NX;
    float* vb   = kb + NX;
    float* ctx  = vb + NX;
    float* hb   = qb;   // FFN intermediate (B*S*DFF == 4*NX) aliases qb..ctx; dead by then
    float* logits = ctx + NX;
    float* numb = logits + (size_t)B_ * S_ * NL_;
    float* denb = numb + B_;

    const int M = B_ * S_;   // 4096
    dim3 blk(256);
    dim3 g768(H_ / 64, M / 64);
    dim3 gff(DFF_ / 64, M / 64);
    dim3 gattn(S_, NHD_, B_);

    embed_ln_kernel<<<M, blk, 0, stream>>>(input_ids, token_emb, pos_emb, ln_emb_s, ln_emb_b, x);

    for (int l = 0; l < L_; ++l) {
        const size_t oHH = (size_t)l * H_ * H_;
        gemm_kernel<0><<<g768, blk, 0, stream>>>(x, Wq + oHH, bq + l * H_, nullptr, qb, M, H_, H_);
        gemm_kernel<0><<<g768, blk, 0, stream>>>(x, Wk + oHH, bk + l * H_, nullptr, kb, M, H_, H_);
        gemm_kernel<0><<<g768, blk, 0, stream>>>(x, Wv + oHH, bv + l * H_, nullptr, vb, M, H_, H_);
        attn_kernel<<<gattn, blk, 0, stream>>>(qb, kb, vb, attn_mask, ctx);
        gemm_kernel<2><<<g768, blk, 0, stream>>>(ctx, Wo + oHH, bo + l * H_, x, y, M, H_, H_);
        ln_kernel<<<M, blk, 0, stream>>>(y, ln1s + l * H_, ln1b + l * H_, x);
        gemm_kernel<1><<<gff, blk, 0, stream>>>(x, W1 + (size_t)l * H_ * DFF_, b1 + l * DFF_, nullptr, hb, M, DFF_, H_);
        gemm_kernel<2><<<g768, blk, 0, stream>>>(hb, W2 + (size_t)l * DFF_ * H_, b2 + l * H_, x, y, M, H_, DFF_);
        ln_kernel<<<M, blk, 0, stream>>>(y, ln2s + l * H_, ln2b + l * H_, x);
    }

    dim3 gcls(1, M / 64);
    gemm_kernel<0><<<gcls, blk, 0, stream>>>(x, cls_W, cls_b, nullptr, logits, M, NL_, H_);
    crf_num_kernel<<<B_, blk, 0, stream>>>(logits, labels, attn_mask, start_trans, end_trans, trans, numb);
    crf_fwd_kernel<<<B_, 64, 0, stream>>>(logits, attn_mask, start_trans, end_trans, trans, denb);
    finalize_kernel<<<1, 64, 0, stream>>>(numb, denb, (float*)d_out);
}

// Round 2
// 5337.356 us; speedup vs baseline: 6.2216x; 6.2216x over previous
//
#include <hip/hip_runtime.h>
#include <hip/hip_bf16.h>
#include <math.h>

#define B_   8
#define S_   512
#define H_   768
#define L_   12
#define NHD_ 12
#define DH_  64
#define DFF_ 3072
#define NL_  19

typedef __bf16 bf16x8 __attribute__((ext_vector_type(8)));
typedef float  f32x4  __attribute__((ext_vector_type(4)));

__device__ __forceinline__ unsigned short f2bf(float f) {
    unsigned int u = __float_as_uint(f);
    u = (u + 0x7fffu + ((u >> 16) & 1u)) >> 16;
    return (unsigned short)u;
}

__device__ __forceinline__ float gelu_f(float x) {
    const float c = 0.7978845608028654f; // sqrt(2/pi)
    float x3 = x * x * x;
    return 0.5f * x * (1.0f + tanhf(c * (x + 0.044715f * x3)));
}

// ---------------------------------------------------------------------------
// Transpose + fp32->bf16 convert: src [K][N] fp32  ->  dst [N][K] bf16
// grid (N/64, K/64), 256 threads.
// ---------------------------------------------------------------------------
__global__ __launch_bounds__(256) void transpose_cvt(
    const float* __restrict__ src, unsigned short* __restrict__ dst,
    int K, int N)
{
    __shared__ float t[64][65];
    const int tid = threadIdx.x;
    const int n0 = blockIdx.x * 64;
    const int k0 = blockIdx.y * 64;
    #pragma unroll
    for (int p = 0; p < 16; ++p) {
        int idx = p * 256 + tid;
        int i = idx >> 6, j = idx & 63;
        t[i][j] = src[(size_t)(k0 + i) * N + n0 + j];
    }
    __syncthreads();
    #pragma unroll
    for (int p = 0; p < 4; ++p) {
        int q = p * 256 + tid;
        int n = q >> 4, kq = q & 15;
        unsigned int w0 = (unsigned int)f2bf(t[kq * 4 + 0][n]) | ((unsigned int)f2bf(t[kq * 4 + 1][n]) << 16);
        unsigned int w1 = (unsigned int)f2bf(t[kq * 4 + 2][n]) | ((unsigned int)f2bf(t[kq * 4 + 3][n]) << 16);
        uint2 w; w.x = w0; w.y = w1;
        *(uint2*)(dst + (size_t)(n0 + n) * K + k0 + kq * 4) = w;
    }
}

__global__ void concat3(const float* __restrict__ a, const float* __restrict__ b,
                        const float* __restrict__ c, float* __restrict__ dst)
{
    int i = blockIdx.x * 256 + threadIdx.x;
    if (i < 3 * H_) dst[i] = (i < H_) ? a[i] : (i < 2 * H_ ? b[i - H_] : c[i - 2 * H_]);
}

// ---------------------------------------------------------------------------
// bf16 MFMA GEMM: C[M,N] = epi(A[M,K] @ Bt[N,K]^T + bias)
// EPI: 0 -> fp32 out; 1 -> gelu -> bf16 out; 2 -> +residual -> fp32 out
// 128x128 block tile, 256 thr (4 waves 2x2, each 64x64 = 4x4 MFMA 16x16x32).
// M%128==0, N%128==0, K%32==0.
// ---------------------------------------------------------------------------
template <int EPI>
__global__ __launch_bounds__(256) void gemm_bf16(
    const unsigned short* __restrict__ A,   // [M][K] bf16
    const unsigned short* __restrict__ Bt,  // [N][K] bf16
    const float* __restrict__ bias,         // [N]
    const float* __restrict__ R,            // [M][N] residual (EPI==2)
    float* __restrict__ Cf,                 // fp32 out (EPI 0,2)
    unsigned short* __restrict__ Cb,        // bf16 out (EPI 1)
    int M, int N, int K)
{
    constexpr int LDT = 40;                 // padded row stride in bf16 elems
    __shared__ __align__(16) unsigned short As[128 * LDT];
    __shared__ __align__(16) unsigned short Bs[128 * LDT];
    const int tid  = threadIdx.x;
    const int lane = tid & 63;
    const int wave = tid >> 6;
    const int wm = wave >> 1, wn = wave & 1;
    const int mbase = blockIdx.y * 128;
    const int nbase = blockIdx.x * 128;

    f32x4 zero4 = {0.f, 0.f, 0.f, 0.f};
    f32x4 acc[4][4];
    #pragma unroll
    for (int mi = 0; mi < 4; ++mi)
        #pragma unroll
        for (int ni = 0; ni < 4; ++ni) acc[mi][ni] = zero4;

    const int srow = tid >> 2;       // staging row (pass p adds 64)
    const int sq   = tid & 3;        // 8-elem quarter

    for (int kk = 0; kk < K; kk += 32) {
        #pragma unroll
        for (int p = 0; p < 2; ++p) {
            int row = srow + p * 64;
            *(uint4*)&As[row * LDT + sq * 8] =
                *(const uint4*)(A + (size_t)(mbase + row) * K + kk + sq * 8);
            *(uint4*)&Bs[row * LDT + sq * 8] =
                *(const uint4*)(Bt + (size_t)(nbase + row) * K + kk + sq * 8);
        }
        __syncthreads();

        bf16x8 af[4], bf[4];
        const int l15 = lane & 15;
        const int koff = (lane >> 4) * 8;
        #pragma unroll
        for (int mi = 0; mi < 4; ++mi)
            af[mi] = *(const bf16x8*)&As[(wm * 64 + mi * 16 + l15) * LDT + koff];
        #pragma unroll
        for (int ni = 0; ni < 4; ++ni)
            bf[ni] = *(const bf16x8*)&Bs[(wn * 64 + ni * 16 + l15) * LDT + koff];

        #pragma unroll
        for (int mi = 0; mi < 4; ++mi)
            #pragma unroll
            for (int ni = 0; ni < 4; ++ni)
                acc[mi][ni] = __builtin_amdgcn_mfma_f32_16x16x32_bf16(
                    af[mi], bf[ni], acc[mi][ni], 0, 0, 0);
        __syncthreads();
    }

    const int r0 = (lane >> 4) * 4;
    const int c0 = lane & 15;
    #pragma unroll
    for (int mi = 0; mi < 4; ++mi) {
        const int gm = mbase + wm * 64 + mi * 16 + r0;
        #pragma unroll
        for (int ni = 0; ni < 4; ++ni) {
            const int gn = nbase + wn * 64 + ni * 16 + c0;
            const float bv = bias[gn];
            #pragma unroll
            for (int r = 0; r < 4; ++r) {
                float vv = acc[mi][ni][r] + bv;
                const size_t off = (size_t)(gm + r) * N + gn;
                if (EPI == 0)      Cf[off] = vv;
                else if (EPI == 1) Cb[off] = f2bf(gelu_f(vv));
                else               Cf[off] = vv + R[off];
            }
        }
    }
}

// ---------------------------------------------------------------------------
// Flash-style attention, fp32 VALU. Block = 64 q rows of one (b,h).
// qkv: [B*S][2304] fp32 (q|k|v each H=768 wide). ctxb out: [B*S][768] bf16.
// 256 thr: thread -> (qr = tid>>2, kg = tid&3). K/V tiles 64x64 in LDS,
// chunk-XOR swizzled for conflict-free reads.
// ---------------------------------------------------------------------------
__global__ __launch_bounds__(256) void attn2(
    const float* __restrict__ qkv, const int* __restrict__ mask,
    unsigned short* __restrict__ ctxb)
{
    const int qt = blockIdx.x, h = blockIdx.y, b = blockIdx.z;
    const int tid = threadIdx.x;
    const int qr = tid >> 2;
    const int kg = tid & 3;

    __shared__ __align__(16) float Ks[64 * 64];
    __shared__ __align__(16) float Vs[64 * 64];
    __shared__ float Ps[64 * 65];
    __shared__ float Ms[64];

    const size_t base = (size_t)b * S_ * 2304 + h * 64;
    const float* qp = qkv + base + (size_t)(qt * 64 + qr) * 2304;
    f32x4 q4[16];
    #pragma unroll
    for (int c = 0; c < 16; ++c) q4[c] = *(const f32x4*)(qp + c * 4);

    float m = -1e30f, l = 0.f;
    float acc[16];
    #pragma unroll
    for (int i = 0; i < 16; ++i) acc[i] = 0.f;

    for (int kt = 0; kt < 8; ++kt) {
        __syncthreads();
        #pragma unroll
        for (int p = 0; p < 4; ++p) {
            int f = p * 256 + tid;          // 0..1023 float4 slots
            int row = f >> 4, c = f & 15;
            int scc = c ^ (row >> 4);
            const float* kp = qkv + base + 768 + (size_t)(kt * 64 + row) * 2304 + c * 4;
            *(f32x4*)&Ks[row * 64 + scc * 4] = *(const f32x4*)kp;
            *(f32x4*)&Vs[row * 64 + scc * 4] = *(const f32x4*)(kp + 768);
        }
        if (tid < 64)
            Ms[tid] = (1.0f - (float)mask[b * S_ + kt * 64 + tid]) * -1e9f;
        __syncthreads();

        float s[16];
        #pragma unroll
        for (int j = 0; j < 16; ++j) s[j] = 0.f;
        #pragma unroll
        for (int c = 0; c < 16; ++c) {
            f32x4 qv = q4[c];
            #pragma unroll
            for (int j = 0; j < 16; ++j) {
                f32x4 kv = *(const f32x4*)&Ks[(kg * 16 + j) * 64 + ((c ^ kg) << 2)];
                s[j] = fmaf(qv[0], kv[0], fmaf(qv[1], kv[1],
                       fmaf(qv[2], kv[2], fmaf(qv[3], kv[3], s[j]))));
            }
        }

        float tm = -1e30f;
        #pragma unroll
        for (int j = 0; j < 16; ++j) {
            s[j] = s[j] * 0.125f + Ms[kg * 16 + j];
            tm = fmaxf(tm, s[j]);
        }
        tm = fmaxf(tm, __shfl_xor(tm, 1));
        tm = fmaxf(tm, __shfl_xor(tm, 2));
        float mnew = fmaxf(m, tm);
        float alpha = __expf(m - mnew);
        float ps = 0.f;
        #pragma unroll
        for (int j = 0; j < 16; ++j) {
            float e = __expf(s[j] - mnew);
            Ps[qr * 65 + kg * 16 + j] = e;
            ps += e;
        }
        ps += __shfl_xor(ps, 1);
        ps += __shfl_xor(ps, 2);
        l = l * alpha + ps;
        m = mnew;
        #pragma unroll
        for (int i = 0; i < 16; ++i) acc[i] *= alpha;
        __syncthreads();

        for (int kk = 0; kk < 64; ++kk) {
            float p = Ps[qr * 65 + kk];
            int swz = kk >> 4;
            #pragma unroll
            for (int i4 = 0; i4 < 4; ++i4) {
                f32x4 vv = *(const f32x4*)&Vs[kk * 64 + (((kg * 4 + i4) ^ swz) << 2)];
                acc[i4 * 4 + 0] = fmaf(p, vv[0], acc[i4 * 4 + 0]);
                acc[i4 * 4 + 1] = fmaf(p, vv[1], acc[i4 * 4 + 1]);
                acc[i4 * 4 + 2] = fmaf(p, vv[2], acc[i4 * 4 + 2]);
                acc[i4 * 4 + 3] = fmaf(p, vv[3], acc[i4 * 4 + 3]);
            }
        }
    }

    float invl = 1.0f / l;
    unsigned short* op = ctxb + (size_t)(b * S_ + qt * 64 + qr) * H_ + h * 64 + kg * 16;
    #pragma unroll
    for (int i = 0; i < 16; ++i) op[i] = f2bf(acc[i] * invl);
}

// ---------------------------------------------------------------------------
// Row LayerNorm; writes fp32 + bf16 copies.
// ---------------------------------------------------------------------------
__global__ __launch_bounds__(256) void ln_kernel(
    const float* __restrict__ in, const float* __restrict__ sc,
    const float* __restrict__ bi, float* __restrict__ out,
    unsigned short* __restrict__ outb)
{
    const int row = blockIdx.x;
    const int tid = threadIdx.x;
    const float* x = in + (size_t)row * H_;
    float v[3], s0 = 0.f, s1 = 0.f;
    #pragma unroll
    for (int r = 0; r < 3; ++r) {
        v[r] = x[tid + r * 256];
        s0 += v[r]; s1 += v[r] * v[r];
    }
    __shared__ float red[8];
    __shared__ float stat[2];
    #pragma unroll
    for (int o = 32; o > 0; o >>= 1) { s0 += __shfl_down(s0, o); s1 += __shfl_down(s1, o); }
    if ((tid & 63) == 0) { red[tid >> 6] = s0; red[4 + (tid >> 6)] = s1; }
    __syncthreads();
    if (tid == 0) {
        float t0 = red[0] + red[1] + red[2] + red[3];
        float t1 = red[4] + red[5] + red[6] + red[7];
        float mean = t0 / H_;
        float var  = t1 / H_ - mean * mean;
        stat[0] = mean;
        stat[1] = rsqrtf(var + 1e-12f);
    }
    __syncthreads();
    float mean = stat[0], rstd = stat[1];
    float* o = out + (size_t)row * H_;
    unsigned short* ob = outb + (size_t)row * H_;
    #pragma unroll
    for (int r = 0; r < 3; ++r) {
        int i = tid + r * 256;
        float rr = (v[r] - mean) * rstd * sc[i] + bi[i];
        o[i] = rr;
        ob[i] = f2bf(rr);
    }
}

__global__ __launch_bounds__(256) void embed_ln_kernel(
    const int* __restrict__ ids, const float* __restrict__ tok,
    const float* __restrict__ pos, const float* __restrict__ sc,
    const float* __restrict__ bi, float* __restrict__ out,
    unsigned short* __restrict__ outb)
{
    const int row = blockIdx.x;
    const int spos = row & (S_ - 1);
    const int tid = threadIdx.x;
    const int id = ids[row];
    const float* t = tok + (size_t)id * H_;
    const float* p = pos + (size_t)spos * H_;
    float v[3], s0 = 0.f, s1 = 0.f;
    #pragma unroll
    for (int r = 0; r < 3; ++r) {
        int i = tid + r * 256;
        v[r] = t[i] + p[i];
        s0 += v[r]; s1 += v[r] * v[r];
    }
    __shared__ float red[8];
    __shared__ float stat[2];
    #pragma unroll
    for (int o = 32; o > 0; o >>= 1) { s0 += __shfl_down(s0, o); s1 += __shfl_down(s1, o); }
    if ((tid & 63) == 0) { red[tid >> 6] = s0; red[4 + (tid >> 6)] = s1; }
    __syncthreads();
    if (tid == 0) {
        float t0 = red[0] + red[1] + red[2] + red[3];
        float t1 = red[4] + red[5] + red[6] + red[7];
        float mean = t0 / H_;
        float var  = t1 / H_ - mean * mean;
        stat[0] = mean;
        stat[1] = rsqrtf(var + 1e-12f);
    }
    __syncthreads();
    float mean = stat[0], rstd = stat[1];
    float* o = out + (size_t)row * H_;
    unsigned short* ob = outb + (size_t)row * H_;
    #pragma unroll
    for (int r = 0; r < 3; ++r) {
        int i = tid + r * 256;
        float rr = (v[r] - mean) * rstd * sc[i] + bi[i];
        o[i] = rr;
        ob[i] = f2bf(rr);
    }
}

// ---------------------------------------------------------------------------
// Classifier SIMT GEMM (N=19, tiny) — fp32.
// ---------------------------------------------------------------------------
__global__ __launch_bounds__(256) void gemm_cls(
    const float* __restrict__ A, const float* __restrict__ W,
    const float* __restrict__ bias, float* __restrict__ C, int M, int N, int K)
{
    __shared__ float As[16][65];
    __shared__ float Ws[16][64];
    const int tid = threadIdx.x;
    const int tx = tid & 15;
    const int ty = tid >> 4;
    const int mbase = blockIdx.y * 64;
    const int nbase = blockIdx.x * 64;
    float acc[4][4] = {};
    for (int kk = 0; kk < K; kk += 16) {
        #pragma unroll
        for (int r = 0; r < 4; ++r) {
            int idx = r * 256 + tid;
            int mm = idx >> 4, k4 = idx & 15;
            As[k4][mm] = A[(size_t)(mbase + mm) * K + kk + k4];
        }
        #pragma unroll
        for (int r = 0; r < 4; ++r) {
            int idx = r * 256 + tid;
            int n = idx & 63, k4 = idx >> 6;
            int gn = nbase + n;
            Ws[k4][n] = (gn < N) ? W[(size_t)(kk + k4) * N + gn] : 0.0f;
        }
        __syncthreads();
        #pragma unroll
        for (int k = 0; k < 16; ++k) {
            float a[4], w[4];
            #pragma unroll
            for (int i = 0; i < 4; ++i) a[i] = As[k][ty * 4 + i];
            #pragma unroll
            for (int j = 0; j < 4; ++j) w[j] = Ws[k][tx * 4 + j];
            #pragma unroll
            for (int i = 0; i < 4; ++i)
                #pragma unroll
                for (int j = 0; j < 4; ++j)
                    acc[i][j] = fmaf(a[i], w[j], acc[i][j]);
        }
        __syncthreads();
    }
    #pragma unroll
    for (int i = 0; i < 4; ++i) {
        int gm = mbase + ty * 4 + i;
        #pragma unroll
        for (int j = 0; j < 4; ++j) {
            int gn = nbase + tx * 4 + j;
            if (gn < N) C[(size_t)gm * N + gn] = acc[i][j] + bias[gn];
        }
    }
}

// ---------------------------------------------------------------------------
// CRF kernels (unchanged from round 0)
// ---------------------------------------------------------------------------
__global__ __launch_bounds__(256) void crf_num_kernel(
    const float* __restrict__ logits, const int* __restrict__ labels,
    const int* __restrict__ mask, const float* __restrict__ start_trans,
    const float* __restrict__ end_trans, const float* __restrict__ trans,
    float* __restrict__ numb)
{
    const int b = blockIdx.x;
    const int tid = threadIdx.x;
    float lsum = 0.f, lmask = 0.f;
    for (int t = tid; t < S_; t += 256) {
        float mf = (float)mask[b * S_ + t];
        lmask += mf;
        if (t >= 1) {
            int lp = labels[b * S_ + t - 1];
            int lc = labels[b * S_ + t];
            float em = logits[((size_t)b * S_ + t) * NL_ + lc];
            lsum += (trans[lp * NL_ + lc] + em) * mf;
        }
    }
    __shared__ float red[8];
    #pragma unroll
    for (int o = 32; o > 0; o >>= 1) { lsum += __shfl_down(lsum, o); lmask += __shfl_down(lmask, o); }
    if ((tid & 63) == 0) { red[tid >> 6] = lsum; red[4 + (tid >> 6)] = lmask; }
    __syncthreads();
    if (tid == 0) {
        float ts = red[0] + red[1] + red[2] + red[3];
        float tm = red[4] + red[5] + red[6] + red[7];
        int l0 = labels[b * S_];
        float nm = start_trans[l0] + logits[(size_t)b * S_ * NL_ + l0] + ts;
        int last = (int)tm - 1;
        int lt = labels[b * S_ + last];
        nm += end_trans[lt];
        numb[b] = nm;
    }
}

__global__ __launch_bounds__(64) void crf_fwd_kernel(
    const float* __restrict__ logits, const int* __restrict__ mask,
    const float* __restrict__ start_trans, const float* __restrict__ end_trans,
    const float* __restrict__ trans, float* __restrict__ denb)
{
    const int b = blockIdx.x;
    const int tid = threadIdx.x;
    __shared__ float alpha[NL_];
    __shared__ float tr[NL_ * NL_];
    for (int i = tid; i < NL_ * NL_; i += 64) tr[i] = trans[i];
    if (tid < NL_) alpha[tid] = start_trans[tid] + logits[(size_t)b * S_ * NL_ + tid];
    __syncthreads();
    for (int t = 1; t < S_; ++t) {
        float nxt = 0.f;
        if (tid < NL_) {
            float mm = -3.4e38f;
            #pragma unroll
            for (int i = 0; i < NL_; ++i) mm = fmaxf(mm, alpha[i] + tr[i * NL_ + tid]);
            float s = 0.f;
            #pragma unroll
            for (int i = 0; i < NL_; ++i) s += expf(alpha[i] + tr[i * NL_ + tid] - mm);
            nxt = logits[((size_t)b * S_ + t) * NL_ + tid] + mm + logf(s);
        }
        __syncthreads();
        if (tid < NL_ && mask[b * S_ + t] > 0) alpha[tid] = nxt;
        __syncthreads();
    }
    if (tid == 0) {
        float mm = -3.4e38f;
        for (int i = 0; i < NL_; ++i) mm = fmaxf(mm, alpha[i] + end_trans[i]);
        float s = 0.f;
        for (int i = 0; i < NL_; ++i) s += expf(alpha[i] + end_trans[i] - mm);
        denb[b] = mm + logf(s);
    }
}

__global__ void finalize_kernel(const float* __restrict__ numb,
                                const float* __restrict__ denb,
                                float* __restrict__ out)
{
    if (threadIdx.x == 0 && blockIdx.x == 0) {
        float s = 0.f;
        for (int b = 0; b < B_; ++b) s += denb[b] - numb[b];
        out[0] = s;
    }
}

// ---------------------------------------------------------------------------
extern "C" void kernel_launch(void* const* d_in, const int* in_sizes, int n_in,
                              void* d_out, int out_size, void* d_ws, size_t ws_size,
                              hipStream_t stream)
{
    const int*   input_ids = (const int*)d_in[0];
    const int*   attn_mask = (const int*)d_in[1];
    const int*   labels    = (const int*)d_in[2];
    const float* token_emb = (const float*)d_in[3];
    const float* pos_emb   = (const float*)d_in[4];
    const float* ln_emb_s  = (const float*)d_in[5];
    const float* ln_emb_b  = (const float*)d_in[6];
    const float* Wq  = (const float*)d_in[7];
    const float* bq  = (const float*)d_in[8];
    const float* Wk  = (const float*)d_in[9];
    const float* bk  = (const float*)d_in[10];
    const float* Wv  = (const float*)d_in[11];
    const float* bv  = (const float*)d_in[12];
    const float* Wo  = (const float*)d_in[13];
    const float* bo  = (const float*)d_in[14];
    const float* ln1s = (const float*)d_in[15];
    const float* ln1b = (const float*)d_in[16];
    const float* W1  = (const float*)d_in[17];
    const float* b1  = (const float*)d_in[18];
    const float* W2  = (const float*)d_in[19];
    const float* b2  = (const float*)d_in[20];
    const float* ln2s = (const float*)d_in[21];
    const float* ln2b = (const float*)d_in[22];
    const float* cls_W = (const float*)d_in[23];
    const float* cls_b = (const float*)d_in[24];
    const float* start_trans = (const float*)d_in[25];
    const float* end_trans   = (const float*)d_in[26];
    const float* trans       = (const float*)d_in[27];

    // ---- workspace carve-up (bytes; every region multiple of 256 B) ----
    char* base = (char*)d_ws;
    const int M = B_ * S_;                                  // 4096
    float*          qkv   = (float*)base;                    // [M][2304] fp32 = 37,748,736 B
    unsigned short* hbb   = (unsigned short*)base;           // [M][3072] bf16 (aliases qkv; qkv dead)
    size_t off = (size_t)M * 2304 * 4;
    float*          x     = (float*)(base + off); off += (size_t)M * H_ * 4;
    float*          y     = (float*)(base + off); off += (size_t)M * H_ * 4;
    unsigned short* xb    = (unsigned short*)(base + off); off += (size_t)M * H_ * 2;
    unsigned short* ctxb  = (unsigned short*)(base + off); off += (size_t)M * H_ * 2;
    unsigned short* WqkvT = (unsigned short*)(base + off); off += (size_t)3 * H_ * H_ * 2;
    unsigned short* WoT   = (unsigned short*)(base + off); off += (size_t)H_ * H_ * 2;
    unsigned short* W1T   = (unsigned short*)(base + off); off += (size_t)DFF_ * H_ * 2;
    unsigned short* W2T   = (unsigned short*)(base + off); off += (size_t)H_ * DFF_ * 2;
    float*          biasc = (float*)(base + off); off += 3 * H_ * 4 + 256;
    float*          logits= (float*)(base + off); off += (size_t)M * NL_ * 4;
    float*          numb  = (float*)(base + off); off += 32;
    float*          denb  = (float*)(base + off); off += 32;

    dim3 blk(256);
    embed_ln_kernel<<<M, blk, 0, stream>>>(input_ids, token_emb, pos_emb, ln_emb_s, ln_emb_b, x, xb);

    for (int l = 0; l < L_; ++l) {
        const size_t oHH = (size_t)l * H_ * H_;
        const size_t oHF = (size_t)l * H_ * DFF_;
        // weight transpose+convert for this layer
        transpose_cvt<<<dim3(12, 12), blk, 0, stream>>>(Wq + oHH, WqkvT,             H_, H_);
        transpose_cvt<<<dim3(12, 12), blk, 0, stream>>>(Wk + oHH, WqkvT + H_ * H_,   H_, H_);
        transpose_cvt<<<dim3(12, 12), blk, 0, stream>>>(Wv + oHH, WqkvT + 2 * H_ * H_, H_, H_);
        transpose_cvt<<<dim3(12, 12), blk, 0, stream>>>(Wo + oHH, WoT, H_, H_);
        transpose_cvt<<<dim3(48, 12), blk, 0, stream>>>(W1 + oHF, W1T, H_, DFF_);
        transpose_cvt<<<dim3(12, 48), blk, 0, stream>>>(W2 + oHF, W2T, DFF_, H_);
        concat3<<<9, blk, 0, stream>>>(bq + l * H_, bk + l * H_, bv + l * H_, biasc);

        // fused QKV projection: [4096][2304]
        gemm_bf16<0><<<dim3(18, 32), blk, 0, stream>>>(xb, WqkvT, biasc, nullptr, qkv, nullptr, M, 3 * H_, H_);
        // attention
        attn2<<<dim3(8, NHD_, B_), blk, 0, stream>>>(qkv, attn_mask, ctxb);
        // output projection + residual
        gemm_bf16<2><<<dim3(6, 32), blk, 0, stream>>>(ctxb, WoT, bo + l * H_, x, y, nullptr, M, H_, H_);
        ln_kernel<<<M, blk, 0, stream>>>(y, ln1s + l * H_, ln1b + l * H_, x, xb);
        // FFN
        gemm_bf16<1><<<dim3(24, 32), blk, 0, stream>>>(xb, W1T, b1 + l * DFF_, nullptr, nullptr, hbb, M, DFF_, H_);
        gemm_bf16<2><<<dim3(6, 32), blk, 0, stream>>>(hbb, W2T, b2 + l * H_, x, y, nullptr, M, H_, DFF_);
        ln_kernel<<<M, blk, 0, stream>>>(y, ln2s + l * H_, ln2b + l * H_, x, xb);
    }

    gemm_cls<<<dim3(1, M / 64), blk, 0, stream>>>(x, cls_W, cls_b, logits, M, NL_, H_);
    crf_num_kernel<<<B_, blk, 0, stream>>>(logits, labels, attn_mask, start_trans, end_trans, trans, numb);
    crf_fwd_kernel<<<B_, 64, 0, stream>>>(logits, attn_mask, start_trans, end_trans, trans, denb);
    finalize_kernel<<<1, 64, 0, stream>>>(numb, denb, (float*)d_out);
}

// Round 3
// 4820.724 us; speedup vs baseline: 6.8884x; 1.1072x over previous
//
#include <hip/hip_runtime.h>
#include <hip/hip_bf16.h>
#include <math.h>

#define B_   8
#define S_   512
#define H_   768
#define L_   12
#define NHD_ 12
#define DH_  64
#define DFF_ 3072
#define NL_  19

typedef __bf16 bf16x8 __attribute__((ext_vector_type(8)));
typedef float  f32x4  __attribute__((ext_vector_type(4)));

__device__ __forceinline__ unsigned short f2bf(float f) {
    unsigned int u = __float_as_uint(f);
    u = (u + 0x7fffu + ((u >> 16) & 1u)) >> 16;
    return (unsigned short)u;
}

__device__ __forceinline__ float gelu_f(float x) {
    const float c = 0.7978845608028654f; // sqrt(2/pi)
    float x3 = x * x * x;
    return 0.5f * x * (1.0f + tanhf(c * (x + 0.044715f * x3)));
}

// async global->LDS, 16B per lane; lds dest must be wave-uniform base + lane*16
__device__ __forceinline__ void load_lds16(const unsigned short* g, unsigned short* l) {
    __builtin_amdgcn_global_load_lds(
        (const __attribute__((address_space(1))) unsigned int*)g,
        (__attribute__((address_space(3))) unsigned int*)l,
        16, 0, 0);
}

// ---------------------------------------------------------------------------
// Per-layer weight prep: 6 transposes (fp32 [K][N] -> bf16 [N][K]) + qkv bias
// concat, one launch. Tile map: [0,576) four HxH weights (144 tiles each),
// [576,1152) W1 (48x12), [1152,1728) W2 (12x48), [1728,1737) bias concat.
// ---------------------------------------------------------------------------
__global__ __launch_bounds__(256) void prep_layer(
    const float* __restrict__ Wq, const float* __restrict__ Wk,
    const float* __restrict__ Wv, const float* __restrict__ Wo,
    const float* __restrict__ W1, const float* __restrict__ W2,
    const float* __restrict__ bq, const float* __restrict__ bk,
    const float* __restrict__ bv,
    unsigned short* __restrict__ WqkvT, unsigned short* __restrict__ WoT,
    unsigned short* __restrict__ W1T, unsigned short* __restrict__ W2T,
    float* __restrict__ biasc)
{
    __shared__ float t[64][65];
    const int tid = threadIdx.x;
    const int id = blockIdx.x;

    if (id >= 1728) {
        int i = (id - 1728) * 256 + tid;
        if (i < 3 * H_) biasc[i] = (i < H_) ? bq[i] : (i < 2 * H_ ? bk[i - H_] : bv[i - 2 * H_]);
        return;
    }

    const float* src; unsigned short* dst; int K, N, bx, by;
    if (id < 576) {
        int wsel = id / 144, tt = id % 144;
        bx = tt % 12; by = tt / 12; K = H_; N = H_;
        src = (wsel == 0) ? Wq : (wsel == 1) ? Wk : (wsel == 2) ? Wv : Wo;
        dst = (wsel < 3) ? (WqkvT + (size_t)wsel * H_ * H_) : WoT;
    } else if (id < 1152) {
        int tt = id - 576; bx = tt % 48; by = tt / 48; K = H_; N = DFF_; src = W1; dst = W1T;
    } else {
        int tt = id - 1152; bx = tt % 12; by = tt / 12; K = DFF_; N = H_; src = W2; dst = W2T;
    }

    const int n0 = bx * 64, k0 = by * 64;
    #pragma unroll
    for (int p = 0; p < 16; ++p) {
        int idx = p * 256 + tid;
        int i = idx >> 6, j = idx & 63;
        t[i][j] = src[(size_t)(k0 + i) * N + n0 + j];
    }
    __syncthreads();
    #pragma unroll
    for (int p = 0; p < 4; ++p) {
        int q = p * 256 + tid;
        int n = q >> 4, kq = q & 15;
        unsigned int w0 = (unsigned int)f2bf(t[kq * 4 + 0][n]) | ((unsigned int)f2bf(t[kq * 4 + 1][n]) << 16);
        unsigned int w1 = (unsigned int)f2bf(t[kq * 4 + 2][n]) | ((unsigned int)f2bf(t[kq * 4 + 3][n]) << 16);
        uint2 w; w.x = w0; w.y = w1;
        *(uint2*)(dst + (size_t)(n0 + n) * K + k0 + kq * 4) = w;
    }
}

// ---------------------------------------------------------------------------
// bf16 MFMA GEMM with async global->LDS staging (m97 structure).
// C[M,N] = epi(A[M,K] @ Bt[N,K]^T + bias); EPI: 0 fp32, 1 gelu->bf16, 2 +res fp32
// 128x128 tile, 256 thr (4 waves 2x2). LDS unpadded: chunk i (16B) at i*16,
// i = row*4 + kchunk — exactly the lane-contiguous order global_load_lds needs.
// ---------------------------------------------------------------------------
template <int EPI>
__global__ __launch_bounds__(256) void gemm_bf16(
    const unsigned short* __restrict__ A,   // [M][K] bf16
    const unsigned short* __restrict__ Bt,  // [N][K] bf16
    const float* __restrict__ bias,         // [N]
    const float* __restrict__ R,            // [M][N] residual (EPI==2)
    float* __restrict__ Cf,                 // fp32 out (EPI 0,2)
    unsigned short* __restrict__ Cb,        // bf16 out (EPI 1)
    int M, int N, int K)
{
    __shared__ __align__(16) unsigned short As[128 * 32];
    __shared__ __align__(16) unsigned short Bs[128 * 32];
    const int tid  = threadIdx.x;
    const int lane = tid & 63;
    const int wave = tid >> 6;
    const int wm = wave >> 1, wn = wave & 1;
    const int mbase = blockIdx.y * 128;
    const int nbase = blockIdx.x * 128;

    f32x4 acc[4][4];
    #pragma unroll
    for (int mi = 0; mi < 4; ++mi)
        #pragma unroll
        for (int ni = 0; ni < 4; ++ni) acc[mi][ni] = (f32x4){0.f, 0.f, 0.f, 0.f};

    const int crow = tid >> 2;           // 0..63
    const int kc   = tid & 3;            // 16B chunk within 32-elem k-slab
    const unsigned short* ag0 = A  + (size_t)(mbase + crow) * K + kc * 8;
    const unsigned short* ag1 = A  + (size_t)(mbase + 64 + crow) * K + kc * 8;
    const unsigned short* bg0 = Bt + (size_t)(nbase + crow) * K + kc * 8;
    const unsigned short* bg1 = Bt + (size_t)(nbase + 64 + crow) * K + kc * 8;
    unsigned short* la0 = As + (size_t)tid * 8;
    unsigned short* la1 = As + (size_t)(256 + tid) * 8;
    unsigned short* lb0 = Bs + (size_t)tid * 8;
    unsigned short* lb1 = Bs + (size_t)(256 + tid) * 8;

    const int fr = lane & 15;
    const int fc = lane >> 4;

    for (int kk = 0; kk < K; kk += 32) {
        load_lds16(ag0 + kk, la0);
        load_lds16(ag1 + kk, la1);
        load_lds16(bg0 + kk, lb0);
        load_lds16(bg1 + kk, lb1);
        __syncthreads();

        bf16x8 af[4], bf[4];
        #pragma unroll
        for (int mi = 0; mi < 4; ++mi)
            af[mi] = *(const bf16x8*)&As[(size_t)(wm * 64 + mi * 16 + fr) * 32 + fc * 8];
        #pragma unroll
        for (int ni = 0; ni < 4; ++ni)
            bf[ni] = *(const bf16x8*)&Bs[(size_t)(wn * 64 + ni * 16 + fr) * 32 + fc * 8];

        #pragma unroll
        for (int mi = 0; mi < 4; ++mi)
            #pragma unroll
            for (int ni = 0; ni < 4; ++ni)
                acc[mi][ni] = __builtin_amdgcn_mfma_f32_16x16x32_bf16(
                    af[mi], bf[ni], acc[mi][ni], 0, 0, 0);
        __syncthreads();
    }

    const int r0 = (lane >> 4) * 4;
    const int c0 = lane & 15;
    #pragma unroll
    for (int mi = 0; mi < 4; ++mi) {
        const int gm = mbase + wm * 64 + mi * 16 + r0;
        #pragma unroll
        for (int ni = 0; ni < 4; ++ni) {
            const int gn = nbase + wn * 64 + ni * 16 + c0;
            const float bv = bias[gn];
            #pragma unroll
            for (int r = 0; r < 4; ++r) {
                float vv = acc[mi][ni][r] + bv;
                const size_t off = (size_t)(gm + r) * N + gn;
                if (EPI == 0)      Cf[off] = vv;
                else if (EPI == 1) Cb[off] = f2bf(gelu_f(vv));
                else               Cf[off] = vv + R[off];
            }
        }
    }
}

// ---------------------------------------------------------------------------
// Flash-style attention, fp32 VALU (unchanged from round 2).
// ---------------------------------------------------------------------------
__global__ __launch_bounds__(256) void attn2(
    const float* __restrict__ qkv, const int* __restrict__ mask,
    unsigned short* __restrict__ ctxb)
{
    const int qt = blockIdx.x, h = blockIdx.y, b = blockIdx.z;
    const int tid = threadIdx.x;
    const int qr = tid >> 2;
    const int kg = tid & 3;

    __shared__ __align__(16) float Ks[64 * 64];
    __shared__ __align__(16) float Vs[64 * 64];
    __shared__ float Ps[64 * 65];
    __shared__ float Ms[64];

    const size_t base = (size_t)b * S_ * 2304 + h * 64;
    const float* qp = qkv + base + (size_t)(qt * 64 + qr) * 2304;
    f32x4 q4[16];
    #pragma unroll
    for (int c = 0; c < 16; ++c) q4[c] = *(const f32x4*)(qp + c * 4);

    float m = -1e30f, l = 0.f;
    float acc[16];
    #pragma unroll
    for (int i = 0; i < 16; ++i) acc[i] = 0.f;

    for (int kt = 0; kt < 8; ++kt) {
        __syncthreads();
        #pragma unroll
        for (int p = 0; p < 4; ++p) {
            int f = p * 256 + tid;
            int row = f >> 4, c = f & 15;
            int scc = c ^ (row >> 4);
            const float* kp = qkv + base + 768 + (size_t)(kt * 64 + row) * 2304 + c * 4;
            *(f32x4*)&Ks[row * 64 + scc * 4] = *(const f32x4*)kp;
            *(f32x4*)&Vs[row * 64 + scc * 4] = *(const f32x4*)(kp + 768);
        }
        if (tid < 64)
            Ms[tid] = (1.0f - (float)mask[b * S_ + kt * 64 + tid]) * -1e9f;
        __syncthreads();

        float s[16];
        #pragma unroll
        for (int j = 0; j < 16; ++j) s[j] = 0.f;
        #pragma unroll
        for (int c = 0; c < 16; ++c) {
            f32x4 qv = q4[c];
            #pragma unroll
            for (int j = 0; j < 16; ++j) {
                f32x4 kv = *(const f32x4*)&Ks[(kg * 16 + j) * 64 + ((c ^ kg) << 2)];
                s[j] = fmaf(qv[0], kv[0], fmaf(qv[1], kv[1],
                       fmaf(qv[2], kv[2], fmaf(qv[3], kv[3], s[j]))));
            }
        }

        float tm = -1e30f;
        #pragma unroll
        for (int j = 0; j < 16; ++j) {
            s[j] = s[j] * 0.125f + Ms[kg * 16 + j];
            tm = fmaxf(tm, s[j]);
        }
        tm = fmaxf(tm, __shfl_xor(tm, 1));
        tm = fmaxf(tm, __shfl_xor(tm, 2));
        float mnew = fmaxf(m, tm);
        float alpha = __expf(m - mnew);
        float ps = 0.f;
        #pragma unroll
        for (int j = 0; j < 16; ++j) {
            float e = __expf(s[j] - mnew);
            Ps[qr * 65 + kg * 16 + j] = e;
            ps += e;
        }
        ps += __shfl_xor(ps, 1);
        ps += __shfl_xor(ps, 2);
        l = l * alpha + ps;
        m = mnew;
        #pragma unroll
        for (int i = 0; i < 16; ++i) acc[i] *= alpha;
        __syncthreads();

        for (int kk = 0; kk < 64; ++kk) {
            float p = Ps[qr * 65 + kk];
            int swz = kk >> 4;
            #pragma unroll
            for (int i4 = 0; i4 < 4; ++i4) {
                f32x4 vv = *(const f32x4*)&Vs[kk * 64 + (((kg * 4 + i4) ^ swz) << 2)];
                acc[i4 * 4 + 0] = fmaf(p, vv[0], acc[i4 * 4 + 0]);
                acc[i4 * 4 + 1] = fmaf(p, vv[1], acc[i4 * 4 + 1]);
                acc[i4 * 4 + 2] = fmaf(p, vv[2], acc[i4 * 4 + 2]);
                acc[i4 * 4 + 3] = fmaf(p, vv[3], acc[i4 * 4 + 3]);
            }
        }
    }

    float invl = 1.0f / l;
    unsigned short* op = ctxb + (size_t)(b * S_ + qt * 64 + qr) * H_ + h * 64 + kg * 16;
    #pragma unroll
    for (int i = 0; i < 16; ++i) op[i] = f2bf(acc[i] * invl);
}

// ---------------------------------------------------------------------------
// Row LayerNorm; writes fp32 + bf16 copies.
// ---------------------------------------------------------------------------
__global__ __launch_bounds__(256) void ln_kernel(
    const float* __restrict__ in, const float* __restrict__ sc,
    const float* __restrict__ bi, float* __restrict__ out,
    unsigned short* __restrict__ outb)
{
    const int row = blockIdx.x;
    const int tid = threadIdx.x;
    const float* x = in + (size_t)row * H_;
    float v[3], s0 = 0.f, s1 = 0.f;
    #pragma unroll
    for (int r = 0; r < 3; ++r) {
        v[r] = x[tid + r * 256];
        s0 += v[r]; s1 += v[r] * v[r];
    }
    __shared__ float red[8];
    __shared__ float stat[2];
    #pragma unroll
    for (int o = 32; o > 0; o >>= 1) { s0 += __shfl_down(s0, o); s1 += __shfl_down(s1, o); }
    if ((tid & 63) == 0) { red[tid >> 6] = s0; red[4 + (tid >> 6)] = s1; }
    __syncthreads();
    if (tid == 0) {
        float t0 = red[0] + red[1] + red[2] + red[3];
        float t1 = red[4] + red[5] + red[6] + red[7];
        float mean = t0 / H_;
        float var  = t1 / H_ - mean * mean;
        stat[0] = mean;
        stat[1] = rsqrtf(var + 1e-12f);
    }
    __syncthreads();
    float mean = stat[0], rstd = stat[1];
    float* o = out + (size_t)row * H_;
    unsigned short* ob = outb + (size_t)row * H_;
    #pragma unroll
    for (int r = 0; r < 3; ++r) {
        int i = tid + r * 256;
        float rr = (v[r] - mean) * rstd * sc[i] + bi[i];
        o[i] = rr;
        ob[i] = f2bf(rr);
    }
}

__global__ __launch_bounds__(256) void embed_ln_kernel(
    const int* __restrict__ ids, const float* __restrict__ tok,
    const float* __restrict__ pos, const float* __restrict__ sc,
    const float* __restrict__ bi, float* __restrict__ out,
    unsigned short* __restrict__ outb)
{
    const int row = blockIdx.x;
    const int spos = row & (S_ - 1);
    const int tid = threadIdx.x;
    const int id = ids[row];
    const float* t = tok + (size_t)id * H_;
    const float* p = pos + (size_t)spos * H_;
    float v[3], s0 = 0.f, s1 = 0.f;
    #pragma unroll
    for (int r = 0; r < 3; ++r) {
        int i = tid + r * 256;
        v[r] = t[i] + p[i];
        s0 += v[r]; s1 += v[r] * v[r];
    }
    __shared__ float red[8];
    __shared__ float stat[2];
    #pragma unroll
    for (int o = 32; o > 0; o >>= 1) { s0 += __shfl_down(s0, o); s1 += __shfl_down(s1, o); }
    if ((tid & 63) == 0) { red[tid >> 6] = s0; red[4 + (tid >> 6)] = s1; }
    __syncthreads();
    if (tid == 0) {
        float t0 = red[0] + red[1] + red[2] + red[3];
        float t1 = red[4] + red[5] + red[6] + red[7];
        float mean = t0 / H_;
        float var  = t1 / H_ - mean * mean;
        stat[0] = mean;
        stat[1] = rsqrtf(var + 1e-12f);
    }
    __syncthreads();
    float mean = stat[0], rstd = stat[1];
    float* o = out + (size_t)row * H_;
    unsigned short* ob = outb + (size_t)row * H_;
    #pragma unroll
    for (int r = 0; r < 3; ++r) {
        int i = tid + r * 256;
        float rr = (v[r] - mean) * rstd * sc[i] + bi[i];
        o[i] = rr;
        ob[i] = f2bf(rr);
    }
}

// ---------------------------------------------------------------------------
// Classifier SIMT GEMM (N=19, tiny) — fp32.
// ---------------------------------------------------------------------------
__global__ __launch_bounds__(256) void gemm_cls(
    const float* __restrict__ A, const float* __restrict__ W,
    const float* __restrict__ bias, float* __restrict__ C, int M, int N, int K)
{
    __shared__ float As[16][65];
    __shared__ float Ws[16][64];
    const int tid = threadIdx.x;
    const int tx = tid & 15;
    const int ty = tid >> 4;
    const int mbase = blockIdx.y * 64;
    const int nbase = blockIdx.x * 64;
    float acc[4][4] = {};
    for (int kk = 0; kk < K; kk += 16) {
        #pragma unroll
        for (int r = 0; r < 4; ++r) {
            int idx = r * 256 + tid;
            int mm = idx >> 4, k4 = idx & 15;
            As[k4][mm] = A[(size_t)(mbase + mm) * K + kk + k4];
        }
        #pragma unroll
        for (int r = 0; r < 4; ++r) {
            int idx = r * 256 + tid;
            int n = idx & 63, k4 = idx >> 6;
            int gn = nbase + n;
            Ws[k4][n] = (gn < N) ? W[(size_t)(kk + k4) * N + gn] : 0.0f;
        }
        __syncthreads();
        #pragma unroll
        for (int k = 0; k < 16; ++k) {
            float a[4], w[4];
            #pragma unroll
            for (int i = 0; i < 4; ++i) a[i] = As[k][ty * 4 + i];
            #pragma unroll
            for (int j = 0; j < 4; ++j) w[j] = Ws[k][tx * 4 + j];
            #pragma unroll
            for (int i = 0; i < 4; ++i)
                #pragma unroll
                for (int j = 0; j < 4; ++j)
                    acc[i][j] = fmaf(a[i], w[j], acc[i][j]);
        }
        __syncthreads();
    }
    #pragma unroll
    for (int i = 0; i < 4; ++i) {
        int gm = mbase + ty * 4 + i;
        #pragma unroll
        for (int j = 0; j < 4; ++j) {
            int gn = nbase + tx * 4 + j;
            if (gn < N) C[(size_t)gm * N + gn] = acc[i][j] + bias[gn];
        }
    }
}

// ---------------------------------------------------------------------------
// CRF numerator per batch (unchanged)
// ---------------------------------------------------------------------------
__global__ __launch_bounds__(256) void crf_num_kernel(
    const float* __restrict__ logits, const int* __restrict__ labels,
    const int* __restrict__ mask, const float* __restrict__ start_trans,
    const float* __restrict__ end_trans, const float* __restrict__ trans,
    float* __restrict__ numb)
{
    const int b = blockIdx.x;
    const int tid = threadIdx.x;
    float lsum = 0.f, lmask = 0.f;
    for (int t = tid; t < S_; t += 256) {
        float mf = (float)mask[b * S_ + t];
        lmask += mf;
        if (t >= 1) {
            int lp = labels[b * S_ + t - 1];
            int lc = labels[b * S_ + t];
            float em = logits[((size_t)b * S_ + t) * NL_ + lc];
            lsum += (trans[lp * NL_ + lc] + em) * mf;
        }
    }
    __shared__ float red[8];
    #pragma unroll
    for (int o = 32; o > 0; o >>= 1) { lsum += __shfl_down(lsum, o); lmask += __shfl_down(lmask, o); }
    if ((tid & 63) == 0) { red[tid >> 6] = lsum; red[4 + (tid >> 6)] = lmask; }
    __syncthreads();
    if (tid == 0) {
        float ts = red[0] + red[1] + red[2] + red[3];
        float tm = red[4] + red[5] + red[6] + red[7];
        int l0 = labels[b * S_];
        float nm = start_trans[l0] + logits[(size_t)b * S_ * NL_ + l0] + ts;
        int last = (int)tm - 1;
        int lt = labels[b * S_ + last];
        nm += end_trans[lt];
        numb[b] = nm;
    }
}

// ---------------------------------------------------------------------------
// CRF forward recursion — wave-synchronous rewrite. One 64-thread block per
// batch. alpha in registers (lane j holds tag j), gathered via __shfl;
// trans column in registers; emissions staged 64 steps at a time into LDS;
// __expf/__logf. No barriers in the step loop.
// ---------------------------------------------------------------------------
__global__ __launch_bounds__(64) void crf_fwd_kernel(
    const float* __restrict__ logits, const int* __restrict__ mask,
    const float* __restrict__ start_trans, const float* __restrict__ end_trans,
    const float* __restrict__ trans, float* __restrict__ denb)
{
    const int b = blockIdx.x;
    const int j = threadIdx.x;
    const bool live = j < NL_;

    float trcol[NL_];
    #pragma unroll
    for (int i = 0; i < NL_; ++i)
        trcol[i] = live ? trans[i * NL_ + j] : 0.f;
    float a = live ? (start_trans[j] + logits[(size_t)b * S_ * NL_ + j]) : -1e30f;

    __shared__ float em[64 * NL_];
    __shared__ int   mk[64];

    for (int t0 = 1; t0 < S_; t0 += 64) {
        const int nt = min(64, S_ - t0);
        for (int f = j; f < nt * NL_; f += 64)
            em[f] = logits[((size_t)b * S_ + t0) * NL_ + f];
        if (j < nt) mk[j] = mask[b * S_ + t0 + j];
        __syncthreads();
        for (int tt = 0; tt < nt; ++tt) {
            float vals[NL_];
            float vmax = -1e30f;
            #pragma unroll
            for (int i = 0; i < NL_; ++i) {
                float ai = __shfl(a, i);
                vals[i] = ai + trcol[i];
                vmax = fmaxf(vmax, vals[i]);
            }
            float s = 0.f;
            #pragma unroll
            for (int i = 0; i < NL_; ++i) s += __expf(vals[i] - vmax);
            float emv = live ? em[tt * NL_ + j] : 0.f;
            float nxt = emv + vmax + __logf(s);
            if (live && mk[tt] > 0) a = nxt;
        }
        __syncthreads();
    }

    float v = live ? (a + end_trans[j]) : -1e30f;
    float m = v;
    #pragma unroll
    for (int o = 32; o > 0; o >>= 1) m = fmaxf(m, __shfl_xor(m, o));
    float e = live ? __expf(v - m) : 0.f;
    #pragma unroll
    for (int o = 32; o > 0; o >>= 1) e += __shfl_xor(e, o);
    if (j == 0) denb[b] = m + __logf(e);
}

__global__ void finalize_kernel(const float* __restrict__ numb,
                                const float* __restrict__ denb,
                                float* __restrict__ out)
{
    if (threadIdx.x == 0 && blockIdx.x == 0) {
        float s = 0.f;
        for (int b = 0; b < B_; ++b) s += denb[b] - numb[b];
        out[0] = s;
    }
}

// ---------------------------------------------------------------------------
extern "C" void kernel_launch(void* const* d_in, const int* in_sizes, int n_in,
                              void* d_out, int out_size, void* d_ws, size_t ws_size,
                              hipStream_t stream)
{
    const int*   input_ids = (const int*)d_in[0];
    const int*   attn_mask = (const int*)d_in[1];
    const int*   labels    = (const int*)d_in[2];
    const float* token_emb = (const float*)d_in[3];
    const float* pos_emb   = (const float*)d_in[4];
    const float* ln_emb_s  = (const float*)d_in[5];
    const float* ln_emb_b  = (const float*)d_in[6];
    const float* Wq  = (const float*)d_in[7];
    const float* bq  = (const float*)d_in[8];
    const float* Wk  = (const float*)d_in[9];
    const float* bk  = (const float*)d_in[10];
    const float* Wv  = (const float*)d_in[11];
    const float* bv  = (const float*)d_in[12];
    const float* Wo  = (const float*)d_in[13];
    const float* bo  = (const float*)d_in[14];
    const float* ln1s = (const float*)d_in[15];
    const float* ln1b = (const float*)d_in[16];
    const float* W1  = (const float*)d_in[17];
    const float* b1  = (const float*)d_in[18];
    const float* W2  = (const float*)d_in[19];
    const float* b2  = (const float*)d_in[20];
    const float* ln2s = (const float*)d_in[21];
    const float* ln2b = (const float*)d_in[22];
    const float* cls_W = (const float*)d_in[23];
    const float* cls_b = (const float*)d_in[24];
    const float* start_trans = (const float*)d_in[25];
    const float* end_trans   = (const float*)d_in[26];
    const float* trans       = (const float*)d_in[27];

    char* base = (char*)d_ws;
    const int M = B_ * S_;                                  // 4096
    float*          qkv   = (float*)base;                    // [M][2304] fp32
    unsigned short* hbb   = (unsigned short*)base;           // [M][3072] bf16 (aliases qkv)
    size_t off = (size_t)M * 2304 * 4;
    float*          x     = (float*)(base + off); off += (size_t)M * H_ * 4;
    float*          y     = (float*)(base + off); off += (size_t)M * H_ * 4;
    unsigned short* xb    = (unsigned short*)(base + off); off += (size_t)M * H_ * 2;
    unsigned short* ctxb  = (unsigned short*)(base + off); off += (size_t)M * H_ * 2;
    unsigned short* WqkvT = (unsigned short*)(base + off); off += (size_t)3 * H_ * H_ * 2;
    unsigned short* WoT   = (unsigned short*)(base + off); off += (size_t)H_ * H_ * 2;
    unsigned short* W1T   = (unsigned short*)(base + off); off += (size_t)DFF_ * H_ * 2;
    unsigned short* W2T   = (unsigned short*)(base + off); off += (size_t)H_ * DFF_ * 2;
    float*          biasc = (float*)(base + off); off += 3 * H_ * 4 + 256;
    float*          logits= (float*)(base + off); off += (size_t)M * NL_ * 4;
    float*          numb  = (float*)(base + off); off += 32;
    float*          denb  = (float*)(base + off); off += 32;

    dim3 blk(256);
    embed_ln_kernel<<<M, blk, 0, stream>>>(input_ids, token_emb, pos_emb, ln_emb_s, ln_emb_b, x, xb);

    for (int l = 0; l < L_; ++l) {
        const size_t oHH = (size_t)l * H_ * H_;
        const size_t oHF = (size_t)l * H_ * DFF_;
        prep_layer<<<1737, blk, 0, stream>>>(
            Wq + oHH, Wk + oHH, Wv + oHH, Wo + oHH, W1 + oHF, W2 + oHF,
            bq + l * H_, bk + l * H_, bv + l * H_,
            WqkvT, WoT, W1T, W2T, biasc);

        gemm_bf16<0><<<dim3(18, 32), blk, 0, stream>>>(xb, WqkvT, biasc, nullptr, qkv, nullptr, M, 3 * H_, H_);
        attn2<<<dim3(8, NHD_, B_), blk, 0, stream>>>(qkv, attn_mask, ctxb);
        gemm_bf16<2><<<dim3(6, 32), blk, 0, stream>>>(ctxb, WoT, bo + l * H_, x, y, nullptr, M, H_, H_);
        ln_kernel<<<M, blk, 0, stream>>>(y, ln1s + l * H_, ln1b + l * H_, x, xb);
        gemm_bf16<1><<<dim3(24, 32), blk, 0, stream>>>(xb, W1T, b1 + l * DFF_, nullptr, nullptr, hbb, M, DFF_, H_);
        gemm_bf16<2><<<dim3(6, 32), blk, 0, stream>>>(hbb, W2T, b2 + l * H_, x, y, nullptr, M, H_, DFF_);
        ln_kernel<<<M, blk, 0, stream>>>(y, ln2s + l * H_, ln2b + l * H_, x, xb);
    }

    gemm_cls<<<dim3(1, M / 64), blk, 0, stream>>>(x, cls_W, cls_b, logits, M, NL_, H_);
    crf_num_kernel<<<B_, blk, 0, stream>>>(logits, labels, attn_mask, start_trans, end_trans, trans, numb);
    crf_fwd_kernel<<<B_, 64, 0, stream>>>(logits, attn_mask, start_trans, end_trans, trans, denb);
    finalize_kernel<<<1, 64, 0, stream>>>(numb, denb, (float*)d_out);
}